// Round 1
// baseline (417.613 us; speedup 1.0000x reference)
//
#include <hip/hip_runtime.h>
#include <hip/hip_bf16.h>

// Problem: N=8192 tokens, D=1024, D_qk=D_v=256, scores scaled by *sqrt(D_qk)=16.
// Pipeline: convert_x (fp32->bf16 hi/lo) -> proj (MFMA GEMM, hi/lo 3-term) ->
//           flash attention (KV-split=4, online softmax) -> combine.

typedef __attribute__((ext_vector_type(8))) short short8;   // 8 bf16 = 4 VGPR (MFMA frag)
typedef __attribute__((ext_vector_type(4))) float f32x4;    // MFMA acc frag
typedef __attribute__((ext_vector_type(4))) unsigned int u32x4; // 16B copy unit

#define MFMA16(a, b, c) __builtin_amdgcn_mfma_f32_16x16x32_bf16((a), (b), (c), 0, 0, 0)

__device__ __forceinline__ unsigned short f2bf(float f) {
    unsigned int u = __builtin_bit_cast(unsigned int, f);
    u += 0x7fffu + ((u >> 16) & 1u);   // RNE
    return (unsigned short)(u >> 16);
}
__device__ __forceinline__ float bf2f(unsigned short h) {
    unsigned int u = ((unsigned int)h) << 16;
    return __builtin_bit_cast(float, u);
}

// ---------------- kernel 1: x fp32 -> xhi + xlo bf16 ----------------
__global__ void convert_x_kernel(const float* __restrict__ x,
                                 unsigned short* __restrict__ xhi,
                                 unsigned short* __restrict__ xlo) {
    int i = blockIdx.x * blockDim.x + threadIdx.x;   // 4 elements per thread
    float4 v = reinterpret_cast<const float4*>(x)[i];
    float f[4] = {v.x, v.y, v.z, v.w};
    ushort4 hi, lo;
    unsigned short th[4], tl[4];
#pragma unroll
    for (int j = 0; j < 4; ++j) {
        th[j] = f2bf(f[j]);
        tl[j] = f2bf(f[j] - bf2f(th[j]));
    }
    hi.x = th[0]; hi.y = th[1]; hi.z = th[2]; hi.w = th[3];
    lo.x = tl[0]; lo.y = tl[1]; lo.z = tl[2]; lo.w = tl[3];
    reinterpret_cast<ushort4*>(xhi)[i] = hi;
    reinterpret_cast<ushort4*>(xlo)[i] = lo;
}

// ---------------- kernel 2: projections ----------------
// Q = 16 * x @ Wq^T (hi/lo split out), K = x @ Wk^T (hi/lo), V^T = (x @ Wv^T)^T (bf16).
// Tile 64x64, 4 waves (each 16 rows x 64 cols), K-step 32, 3-term hi/lo MFMA.
__launch_bounds__(256, 4)
__global__ void proj_kernel(const unsigned short* __restrict__ xhi,
                            const unsigned short* __restrict__ xlo,
                            const float* __restrict__ Wq, const float* __restrict__ Wk,
                            const float* __restrict__ Wv,
                            unsigned short* __restrict__ Qhi, unsigned short* __restrict__ Qlo,
                            unsigned short* __restrict__ Khi, unsigned short* __restrict__ Klo,
                            unsigned short* __restrict__ VT) {
    __shared__ __align__(16) unsigned short xh[64 * 32], xl[64 * 32];
    __shared__ __align__(16) unsigned short wh[64 * 32], wl[64 * 32];
    const int t = threadIdx.x;
    const int mtile = blockIdx.x;
    const int y = blockIdx.y;
    const int w = y >> 2, nt = y & 3;
    const int mb = mtile * 64, nb = nt * 64;
    const float* W = (w == 0) ? Wq : (w == 1) ? Wk : Wv;
    const int wid = t >> 6, lane = t & 63, lr = lane & 15, lg = lane >> 4;

    const f32x4 fzero = {0.f, 0.f, 0.f, 0.f};
    f32x4 acc[4];
#pragma unroll
    for (int i = 0; i < 4; ++i) acc[i] = fzero;

    for (int ks = 0; ks < 32; ++ks) {
        const int k0 = ks * 32;
        {   // stage x hi/lo tile [64][32] bf16 — 1x16B per thread per array
            int row = t >> 2, cb = t & 3;
            int g = (mb + row) * 1024 + k0 + cb * 8;
            int idx = (row * 32 + cb * 8) ^ ((row & 7) << 3);
            *reinterpret_cast<u32x4*>(&xh[idx]) = *reinterpret_cast<const u32x4*>(xhi + g);
            *reinterpret_cast<u32x4*>(&xl[idx]) = *reinterpret_cast<const u32x4*>(xlo + g);
        }
#pragma unroll
        for (int p = 0; p < 2; ++p) {   // stage W tile [64][32] fp32 -> hi/lo bf16
            int c = p * 256 + t;
            int row = c >> 3, fb = c & 7;
            float4 v = *reinterpret_cast<const float4*>(W + (nb + row) * 1024 + k0 + fb * 4);
            float ff[4] = {v.x, v.y, v.z, v.w};
            ushort4 hh, ll;
            unsigned short th[4], tl[4];
#pragma unroll
            for (int j = 0; j < 4; ++j) {
                th[j] = f2bf(ff[j]);
                tl[j] = f2bf(ff[j] - bf2f(th[j]));
            }
            hh.x = th[0]; hh.y = th[1]; hh.z = th[2]; hh.w = th[3];
            ll.x = tl[0]; ll.y = tl[1]; ll.z = tl[2]; ll.w = tl[3];
            int idx = (row * 32 + fb * 4) ^ ((row & 7) << 3);
            *reinterpret_cast<ushort4*>(&wh[idx]) = hh;
            *reinterpret_cast<ushort4*>(&wl[idx]) = ll;
        }
        __syncthreads();
        {
            int arow = wid * 16 + lr;
            int aidx = (arow * 32 + lg * 8) ^ ((arow & 7) << 3);
            short8 ah = *reinterpret_cast<const short8*>(&xh[aidx]);
            short8 al = *reinterpret_cast<const short8*>(&xl[aidx]);
#pragma unroll
            for (int ct = 0; ct < 4; ++ct) {
                int brow = ct * 16 + lr;
                int bidx = (brow * 32 + lg * 8) ^ ((brow & 7) << 3);
                short8 bh = *reinterpret_cast<const short8*>(&wh[bidx]);
                short8 bl = *reinterpret_cast<const short8*>(&wl[bidx]);
                acc[ct] = MFMA16(ah, bh, acc[ct]);
                acc[ct] = MFMA16(ah, bl, acc[ct]);
                acc[ct] = MFMA16(al, bh, acc[ct]);
            }
        }
        __syncthreads();
    }
    // epilogue: C layout col=lane&15, row=(lane>>4)*4+j
    const int rbase = mb + wid * 16 + lg * 4;
#pragma unroll
    for (int ct = 0; ct < 4; ++ct) {
        int col = nb + ct * 16 + lr;
        if (w == 2) {   // V: store transposed VT[col][row], 4 contiguous rows
            ushort4 v4;
            v4.x = f2bf(acc[ct][0]); v4.y = f2bf(acc[ct][1]);
            v4.z = f2bf(acc[ct][2]); v4.w = f2bf(acc[ct][3]);
            *reinterpret_cast<ushort4*>(VT + (size_t)col * 8192 + rbase) = v4;
        } else {
            unsigned short* Hi = (w == 0) ? Qhi : Khi;
            unsigned short* Lo = (w == 0) ? Qlo : Klo;
            const float scale = (w == 0) ? 16.0f : 1.0f;   // fold sqrt(D_qk) into Q (exact, pow2)
#pragma unroll
            for (int j = 0; j < 4; ++j) {
                float v = acc[ct][j] * scale;
                unsigned short h = f2bf(v);
                unsigned short lo = f2bf(v - bf2f(h));
                Hi[(size_t)(rbase + j) * 256 + col] = h;
                Lo[(size_t)(rbase + j) * 256 + col] = lo;
            }
        }
    }
}

// ---------------- kernel 3: flash attention ----------------
// BM=128 (8 waves x 16 rows), KVBLK=32, KV-split=4 (2048 rows each).
// S = Qhi*Khi + Qhi*Klo + Qlo*Khi (fp32-grade scores), online softmax, P bf16, PV MFMA.
__launch_bounds__(512, 2)
__global__ void flash_kernel(const unsigned short* __restrict__ Qhi,
                             const unsigned short* __restrict__ Qlo,
                             const unsigned short* __restrict__ Khi_g,
                             const unsigned short* __restrict__ Klo_g,
                             const unsigned short* __restrict__ VT,
                             float* __restrict__ Opart, float* __restrict__ Mpart,
                             float* __restrict__ Lpart) {
    __shared__ __align__(16) unsigned short Kh[32 * 256], Kl[32 * 256];
    __shared__ __align__(16) unsigned short Vt[256 * 32];
    __shared__ __align__(16) unsigned short Pb[8 * 16 * 32];
    const int t = threadIdx.x;
    // chunked XCD swizzle: XCD k gets a contiguous work range (same split stays L2-hot)
    const int bid = blockIdx.x;
    const int work = (bid & 7) * 32 + (bid >> 3);
    const int split = work >> 6, mtile = work & 63;
    const int mb = mtile * 128;
    const int kv0 = split * 2048;
    const int wid = t >> 6, lane = t & 63, lr = lane & 15, lg = lane >> 4;

    // Q in registers (A-frag layout): row = lane&15, k = (lane>>4)*8 + j, 8 K-steps
    const int qrow = mb + wid * 16 + lr;
    short8 qh[8], ql[8];
#pragma unroll
    for (int ko = 0; ko < 8; ++ko) {
        int g = qrow * 256 + ko * 32 + lg * 8;
        qh[ko] = *reinterpret_cast<const short8*>(Qhi + g);
        ql[ko] = *reinterpret_cast<const short8*>(Qlo + g);
    }
    const f32x4 fzero = {0.f, 0.f, 0.f, 0.f};
    f32x4 acc[16];
#pragma unroll
    for (int i = 0; i < 16; ++i) acc[i] = fzero;
    float m[4], l[4];
#pragma unroll
    for (int j = 0; j < 4; ++j) { m[j] = -__builtin_inff(); l[j] = 0.f; }
    unsigned short* Pw = Pb + wid * 512;

    for (int it = 0; it < 64; ++it) {
        const int kvb = kv0 + it * 32;
        // ---- stage Kh/Kl [32][256] and Vt [256][32] (XOR-swizzled) ----
#pragma unroll
        for (int p = 0; p < 2; ++p) {
            int c = p * 512 + t;
            {
                int row = c >> 5, cb = c & 31;
                int g = (kvb + row) * 256 + cb * 8;
                int idx = (row * 256 + cb * 8) ^ ((row & 7) << 3);
                *reinterpret_cast<u32x4*>(&Kh[idx]) = *reinterpret_cast<const u32x4*>(Khi_g + g);
                *reinterpret_cast<u32x4*>(&Kl[idx]) = *reinterpret_cast<const u32x4*>(Klo_g + g);
            }
            {
                int row = c >> 2, cb = c & 3;
                int g = row * 8192 + kvb + cb * 8;
                int idx = (row * 32 + cb * 8) ^ ((row & 7) << 3);
                *reinterpret_cast<u32x4*>(&Vt[idx]) = *reinterpret_cast<const u32x4*>(VT + g);
            }
        }
        __syncthreads();
        // ---- S = Q * K^T  (16 q-rows x 32 kv-cols per wave) ----
        f32x4 s0 = fzero, s1 = fzero;
#pragma unroll
        for (int ko = 0; ko < 8; ++ko) {
            int b0 = (lr * 256 + ko * 32 + lg * 8) ^ ((lr & 7) << 3);
            int b1 = ((16 + lr) * 256 + ko * 32 + lg * 8) ^ ((lr & 7) << 3);
            short8 bh0 = *reinterpret_cast<const short8*>(&Kh[b0]);
            short8 bl0 = *reinterpret_cast<const short8*>(&Kl[b0]);
            short8 bh1 = *reinterpret_cast<const short8*>(&Kh[b1]);
            short8 bl1 = *reinterpret_cast<const short8*>(&Kl[b1]);
            s0 = MFMA16(qh[ko], bh0, s0);
            s1 = MFMA16(qh[ko], bh1, s1);
            s0 = MFMA16(qh[ko], bl0, s0);
            s1 = MFMA16(qh[ko], bl1, s1);
            s0 = MFMA16(ql[ko], bh0, s0);
            s1 = MFMA16(ql[ko], bh1, s1);
        }
        // ---- online softmax (rows live in 16-lane groups; reduce over kv via shfl) ----
#pragma unroll
        for (int j = 0; j < 4; ++j) {
            float mx = fmaxf(s0[j], s1[j]);
            mx = fmaxf(mx, __shfl_xor(mx, 1));
            mx = fmaxf(mx, __shfl_xor(mx, 2));
            mx = fmaxf(mx, __shfl_xor(mx, 4));
            mx = fmaxf(mx, __shfl_xor(mx, 8));
            float nm = fmaxf(m[j], mx);
            float sc = __expf(m[j] - nm);
            float p0 = __expf(s0[j] - nm);
            float p1 = __expf(s1[j] - nm);
            float rs = p0 + p1;
            rs += __shfl_xor(rs, 1);
            rs += __shfl_xor(rs, 2);
            rs += __shfl_xor(rs, 4);
            rs += __shfl_xor(rs, 8);
            l[j] = l[j] * sc + rs;
            m[j] = nm;
#pragma unroll
            for (int dt = 0; dt < 16; ++dt) acc[dt][j] *= sc;
            int prow = lg * 4 + j;
            int sw = (prow & 7) << 3;
            Pw[(prow * 32 + lr) ^ sw] = f2bf(p0);
            Pw[(prow * 32 + 16 + lr) ^ sw] = f2bf(p1);
        }
        asm volatile("s_waitcnt lgkmcnt(0)" ::: "memory");   // wave-local P write->read
        short8 pa = *reinterpret_cast<const short8*>(&Pw[(lr * 32 + lg * 8) ^ ((lr & 7) << 3)]);
        // ---- O += P * V ----
#pragma unroll
        for (int dt = 0; dt < 16; ++dt) {
            int vrow = dt * 16 + lr;
            int vidx = (vrow * 32 + lg * 8) ^ ((vrow & 7) << 3);
            short8 bv = *reinterpret_cast<const short8*>(&Vt[vidx]);
            acc[dt] = MFMA16(pa, bv, acc[dt]);
        }
        __syncthreads();
    }
    // ---- epilogue: unnormalized O + per-row (m, l) ----
    float* Ob = Opart + (size_t)split * 8192 * 256;
    const int rb = mb + wid * 16 + lg * 4;
#pragma unroll
    for (int j = 0; j < 4; ++j) {
#pragma unroll
        for (int dt = 0; dt < 16; ++dt) {
            Ob[(size_t)(rb + j) * 256 + dt * 16 + lr] = acc[dt][j];
        }
        if (lr == 0) {
            Mpart[split * 8192 + rb + j] = m[j];
            Lpart[split * 8192 + rb + j] = l[j];
        }
    }
}

// ---------------- kernel 4: combine KV-split partials ----------------
__global__ void combine_kernel(const float* __restrict__ Opart, const float* __restrict__ Mpart,
                               const float* __restrict__ Lpart, float* __restrict__ out) {
    const int row = blockIdx.x;
    const int d = threadIdx.x;
    float mm = -__builtin_inff();
#pragma unroll
    for (int s = 0; s < 4; ++s) mm = fmaxf(mm, Mpart[s * 8192 + row]);
    float num = 0.f, den = 0.f;
#pragma unroll
    for (int s = 0; s < 4; ++s) {
        float w = __expf(Mpart[s * 8192 + row] - mm);
        den += w * Lpart[s * 8192 + row];
        num += w * Opart[((size_t)s * 8192 + row) * 256 + d];
    }
    out[(size_t)row * 256 + d] = num / den;
}

extern "C" void kernel_launch(void* const* d_in, const int* in_sizes, int n_in,
                              void* d_out, int out_size, void* d_ws, size_t ws_size,
                              hipStream_t stream) {
    const float* x  = (const float*)d_in[0];
    const float* Wq = (const float*)d_in[1];
    const float* Wk = (const float*)d_in[2];
    const float* Wv = (const float*)d_in[3];
    float* out = (float*)d_out;

    char* ws = (char*)d_ws;
    const size_t SZ_QK = (size_t)8192 * 256 * 2;     // 4 MiB per bf16 array
    unsigned short* Qhi = (unsigned short*)(ws + 0 * SZ_QK);
    unsigned short* Qlo = (unsigned short*)(ws + 1 * SZ_QK);
    unsigned short* Khi = (unsigned short*)(ws + 2 * SZ_QK);
    unsigned short* Klo = (unsigned short*)(ws + 3 * SZ_QK);
    unsigned short* VT  = (unsigned short*)(ws + 4 * SZ_QK);
    float* Mpart = (float*)(ws + 5 * SZ_QK);
    float* Lpart = (float*)(ws + 5 * SZ_QK + 131072);
    char* uA = ws + 5 * SZ_QK + 262144;              // union region:
    unsigned short* xhi = (unsigned short*)uA;       //   phase A: xhi (16 MiB) + xlo (16 MiB)
    unsigned short* xlo = (unsigned short*)(uA + (size_t)8192 * 1024 * 2);
    float* Opart = (float*)uA;                       //   phase B: Opart (32 MiB) aliases xhi/xlo

    convert_x_kernel<<<8192, 256, 0, stream>>>(x, xhi, xlo);
    proj_kernel<<<dim3(128, 12), 256, 0, stream>>>(xhi, xlo, Wq, Wk, Wv,
                                                   Qhi, Qlo, Khi, Klo, VT);
    flash_kernel<<<256, 512, 0, stream>>>(Qhi, Qlo, Khi, Klo, VT, Opart, Mpart, Lpart);
    combine_kernel<<<8192, 256, 0, stream>>>(Opart, Mpart, Lpart, out);
}